// Round 16
// baseline (400.227 us; speedup 1.0000x reference)
//
#include <hip/hip_runtime.h>
#include <cstddef>

typedef unsigned short u16;
using short8 = __attribute__((ext_vector_type(8))) short;
using f32x4  = __attribute__((ext_vector_type(4))) float;

__device__ __forceinline__ float bf2f(u16 u) {
  union { unsigned int i; float f; } v; v.i = ((unsigned int)u) << 16; return v.f;
}
__device__ __forceinline__ u16 f2bf(float f) {
  __bf16 h = (__bf16)f;
  return __builtin_bit_cast(unsigned short, h);
}

// async global(16B/lane) -> LDS. lds dest must be wave-uniform base; HW adds lane*16.
__device__ __forceinline__ void load_lds16(const u16* g, u16* l) {
  __builtin_amdgcn_global_load_lds((const __attribute__((address_space(1))) void*)g,
                                   (__attribute__((address_space(3))) void*)l, 16, 0, 0);
}

// ---------------------------------------------------------------------------
// Batched 2D transpose + fp32->bf16: in fp32 [R][C] -> out bf16 [C][R].
// Grid: (C/32, R/32, nBatch), block (32,8). R,C multiples of 32.
// ---------------------------------------------------------------------------
__global__ __launch_bounds__(256) void transpose_k(const float* __restrict__ in,
                                                   u16* __restrict__ out,
                                                   int R, int C,
                                                   long inB, long outB) {
  __shared__ float tile[32][33];
  long zb = blockIdx.z;
  in  += zb * inB;
  out += zb * outB;
  int c0 = blockIdx.x * 32, r0 = blockIdx.y * 32;
  int tx = threadIdx.x, ty = threadIdx.y;
#pragma unroll
  for (int i = 0; i < 32; i += 8)
    tile[ty + i][tx] = in[(long)(r0 + ty + i) * C + c0 + tx];
  __syncthreads();
#pragma unroll
  for (int i = 0; i < 32; i += 8)
    out[(long)(c0 + ty + i) * R + r0 + tx] = f2bf(tile[tx][ty + i]);
}

// ---------------------------------------------------------------------------
// V transpose: qkv [b*2048][3072] (V at col 2048+h*64+e) -> vT[(b*16+h)*64+e][2048]
// Grid (2, 64, 32), block (32,8).
// ---------------------------------------------------------------------------
__global__ __launch_bounds__(256) void transpose_v_k(const u16* __restrict__ qkv,
                                                     u16* __restrict__ vT) {
  __shared__ u16 tile[32][33];
  int bh = blockIdx.z;
  int b = bh >> 4, h = bh & 15;
  const u16* in = qkv + (size_t)b * 2048 * 3072 + 2048 + h * 64;
  u16* out = vT + (size_t)bh * 64 * 2048;
  int e0 = blockIdx.x * 32, s0 = blockIdx.y * 32;
  int tx = threadIdx.x, ty = threadIdx.y;
#pragma unroll
  for (int i = 0; i < 32; i += 8)
    tile[ty + i][tx] = in[(size_t)(s0 + ty + i) * 3072 + e0 + tx];
  __syncthreads();
#pragma unroll
  for (int i = 0; i < 32; i += 8)
    out[(size_t)(e0 + ty + i) * 2048 + s0 + tx] = tile[tx][ty + i];
}

// ---------------------------------------------------------------------------
// Combined QKV bias (fp32): [0..1023]=b_Q, [1024..2047]=b_K, [2048..3071]=b_V
// ---------------------------------------------------------------------------
__global__ void build_qkv_bias(const float* __restrict__ bQ, const float* __restrict__ bK,
                               const float* __restrict__ bV, float* __restrict__ out) {
  int i = blockIdx.x * 256 + threadIdx.x;
  float v;
  if (i < 1024) v = bQ[i];
  else if (i < 2048) v = bK[i - 1024];
  else v = bV[i - 2048];
  out[i] = v;
}

// ---------------------------------------------------------------------------
// LayerNorm over D=1024, fp32 in -> bf16 out. One block (256 thr) per row.
// ---------------------------------------------------------------------------
__global__ __launch_bounds__(256) void ln_k(const float* __restrict__ inp,
                                            const float* __restrict__ w,
                                            const float* __restrict__ bias,
                                            u16* __restrict__ out) {
  __shared__ float red[2][4];
  int row = blockIdx.x, t = threadIdx.x;
  int wave = t >> 6, lane = t & 63;
  size_t base = (size_t)row * 1024 + t * 4;
  float4 f = *(const float4*)(inp + base);
  float v[4] = {f.x, f.y, f.z, f.w};
  float s = v[0] + v[1] + v[2] + v[3];
#pragma unroll
  for (int off = 32; off; off >>= 1) s += __shfl_xor(s, off, 64);
  if (lane == 0) red[0][wave] = s;
  __syncthreads();
  float mean = (red[0][0] + red[0][1] + red[0][2] + red[0][3]) * (1.f / 1024.f);
  float c[4]; float sq = 0.f;
#pragma unroll
  for (int j = 0; j < 4; ++j) { c[j] = v[j] - mean; sq += c[j] * c[j]; }
#pragma unroll
  for (int off = 32; off; off >>= 1) sq += __shfl_xor(sq, off, 64);
  if (lane == 0) red[1][wave] = sq;
  __syncthreads();
  float var = (red[1][0] + red[1][1] + red[1][2] + red[1][3]) * (1.f / 1024.f);
  float inv = 1.f / sqrtf(var + 1e-5f);
  float4 wv = *(const float4*)(w + t * 4);
  float4 bv = *(const float4*)(bias + t * 4);
  out[base + 0] = f2bf(c[0] * inv * wv.x + bv.x);
  out[base + 1] = f2bf(c[1] * inv * wv.y + bv.y);
  out[base + 2] = f2bf(c[2] * inv * wv.z + bv.z);
  out[base + 3] = f2bf(c[3] * inv * wv.w + bv.w);
}

// ---------------------------------------------------------------------------
// m97-class MFMA GEMM: C[M][N] = A[M][K](bf16) * BT[N][K](bf16)^T + bias(f32)
// 128xTN tile (TN=128 or 64), BK=64, global_load_lds 16B staging, XOR-swizzled
// LDS (16B slot = seg ^ (row&7)). 4 waves in 2x2; wave tile 64 x TN/2.
// Grid (N/TN, M/128), block 256.
// ---------------------------------------------------------------------------
template<int TN, bool RESIDF, bool GELU, bool OUTF32>
__global__ __launch_bounds__(256, 2) void gemm_k(const u16* __restrict__ A,
                                                 const u16* __restrict__ BT,
                                                 const float* __restrict__ bias,
                                                 const float* __restrict__ resid,
                                                 void* __restrict__ Cout,
                                                 int M, int N, int K) {
  constexpr int NS = TN / 32;   // 16-col n-subtiles per wave
  __shared__ u16 As[128 * 64];
  __shared__ u16 Bs[TN * 64];
  int n0 = blockIdx.x * TN, m0 = blockIdx.y * 128;
  int t = threadIdx.x;
  int wave = t >> 6, lane = t & 63;
  int wr = wave >> 1, wc = wave & 1;
  int ln16 = lane & 15, quad = lane >> 4;

  f32x4 acc[4][NS];
#pragma unroll
  for (int i = 0; i < 4; ++i)
#pragma unroll
    for (int j = 0; j < NS; ++j) acc[i][j] = (f32x4){0.f, 0.f, 0.f, 0.f};

  int lrow8 = lane >> 3;
  int gseg  = (lane & 7) ^ lrow8;
  const u16* aG = A  + (size_t)(m0 + wave * 8 + lrow8) * K + gseg * 8;
  const u16* bG = BT + (size_t)(n0 + wave * 8 + lrow8) * K + gseg * 8;
  u16* aL = As + wave * 8 * 64;
  u16* bL = Bs + wave * 8 * 64;

  int e = ln16 & 7;
  int arow = wr * 64 + ln16;
  int brow = wc * (TN / 2) + ln16;

  for (int k0 = 0; k0 < K; k0 += 64) {
    __syncthreads();
#pragma unroll
    for (int i = 0; i < 4; ++i)
      load_lds16(aG + (size_t)i * 32 * K + k0, aL + i * 32 * 64);
#pragma unroll
    for (int i = 0; i < TN / 32; ++i)
      load_lds16(bG + (size_t)i * 32 * K + k0, bL + i * 32 * 64);
    __syncthreads();
#pragma unroll
    for (int kk = 0; kk < 2; ++kk) {
      int slot = (kk * 4 + quad) ^ e;
      short8 af[4], bf[NS];
#pragma unroll
      for (int ms = 0; ms < 4; ++ms)
        af[ms] = *(const short8*)&As[(arow + ms * 16) * 64 + slot * 8];
#pragma unroll
      for (int ns = 0; ns < NS; ++ns)
        bf[ns] = *(const short8*)&Bs[(brow + ns * 16) * 64 + slot * 8];
#pragma unroll
      for (int ms = 0; ms < 4; ++ms)
#pragma unroll
        for (int ns = 0; ns < NS; ++ns)
          acc[ms][ns] = __builtin_amdgcn_mfma_f32_16x16x32_bf16(af[ms], bf[ns], acc[ms][ns], 0, 0, 0);
    }
  }

#pragma unroll
  for (int ms = 0; ms < 4; ++ms)
#pragma unroll
    for (int ns = 0; ns < NS; ++ns)
#pragma unroll
      for (int r = 0; r < 4; ++r) {
        int grow = m0 + wr * 64 + ms * 16 + quad * 4 + r;
        int gcol = n0 + wc * (TN / 2) + ns * 16 + ln16;
        size_t idx = (size_t)grow * N + gcol;
        float v = acc[ms][ns][r] + bias[gcol];
        if (GELU) v = 0.5f * v * (1.f + erff(v * 0.70710678118654752f));
        if (RESIDF) v += resid[idx];
        if (OUTF32) ((float*)Cout)[idx] = v;
        else        ((u16*)Cout)[idx] = f2bf(v);
      }
}

// ---------------------------------------------------------------------------
// 256x256 phase-pipelined MFMA GEMM (counted-vmcnt schedule, T3+T4+T5).
// C[M][N](bf16) = A[M][K](bf16) * BT[N][K]^T + bias, optional exact GELU.
// 512 threads = 8 waves in 2(M) x 4(N); per-wave output 128x64.
// LDS ring of 4 K-half slots. NEW (r15): slot re-laid out as [128 R][64 u16]
// (128B rows): LDS row R holds global m-rows {2R, 2R+1}; physical 16B slot
// S_phys = S_log ^ (R&7) with S_log = 4*(m&1) + seg. This is the gemm_k
// geometry measured at 0 bank conflicts; the old 64B-row linear layout
// measured 3.1M conflicts/dispatch (8-lane groups hit only 2 bank regions).
// Staging stays LDS-linear (global_load_lds); the inverse swizzle is folded
// into the per-lane GLOBAL source address; reads apply the same involution.
// vmcnt schedule unchanged: prologue 3 slots, steady vmcnt(8), tail 8->4->0.
// Requires K%32==0, K>=128, M%256==0, N%256==0.
// ---------------------------------------------------------------------------
template<bool GELU>
__global__ __launch_bounds__(512, 2) void gemm256_k(const u16* __restrict__ A,
                                                    const u16* __restrict__ BT,
                                                    const float* __restrict__ bias,
                                                    u16* __restrict__ C,
                                                    int M, int N, int K) {
  constexpr int SLOT = 8192;                 // u16 per ring slot (128 R x 64)
  __shared__ __align__(16) u16 As[4 * SLOT]; // 64 KB
  __shared__ __align__(16) u16 Bs[4 * SLOT]; // 64 KB
  int n0 = blockIdx.x * 256, m0 = blockIdx.y * 256;
  int t = threadIdx.x;
  int w = t >> 6, lane = t & 63;
  int wr = w >> 2, wc = w & 3;
  int ln16 = lane & 15, quad = lane >> 4;

  f32x4 acc[8][4];
#pragma unroll
  for (int i = 0; i < 8; ++i)
#pragma unroll
    for (int j = 0; j < 4; ++j) acc[i][j] = (f32x4){0.f, 0.f, 0.f, 0.f};

  // Staging: lane l writes 16B at LDS linear (w*1024 + l*8 u16) -> R = w*16 +
  // (l>>3) [+8 for instr 1], S_phys = l&7. Required global content:
  // S_log = (l&7) ^ (l>>3)  [R&7 = l>>3 since w*16, i*8 == 0 mod 8]
  // m_local = w*32 + i*16 + 2*(l>>3) + (S_log>>2), seg = S_log&3.
  int sl = (lane & 7) ^ (lane >> 3);
  const u16* aG0 = A  + (size_t)(m0 + w * 32 + 2 * (lane >> 3) + (sl >> 2)) * K + (sl & 3) * 8;
  const u16* bG0 = BT + (size_t)(n0 + w * 32 + 2 * (lane >> 3) + (sl >> 2)) * K + (sl & 3) * 8;
  u16* aL0 = As + w * 1024;   // +tg*SLOT at use; +512 for instr 1 (8 R-rows)
  u16* bL0 = Bs + w * 1024;

#define STAGE_A(j, tg) do {                                         \
    const u16* _g = aG0 + (size_t)(j) * 32;                         \
    u16* _l = aL0 + (tg) * SLOT;                                    \
    load_lds16(_g, _l);                                             \
    load_lds16(_g + (size_t)16 * K, _l + 512);                      \
  } while (0)
#define STAGE_B(j, tg) do {                                         \
    const u16* _g = bG0 + (size_t)(j) * 32;                         \
    u16* _l = bL0 + (tg) * SLOT;                                    \
    load_lds16(_g, _l);                                             \
    load_lds16(_g + (size_t)16 * K, _l + 512);                      \
  } while (0)

  // prologue: slots 0,1,2 in flight; confirm slot 0
  STAGE_A(0, 0); STAGE_B(0, 0);
  STAGE_A(1, 1); STAGE_B(1, 1);
  STAGE_A(2, 2); STAGE_B(2, 2);
  asm volatile("s_waitcnt vmcnt(8)" ::: "memory");
  __builtin_amdgcn_s_barrier();

  int nslot = K >> 5;
  // Read: fragment i -> m = base + i*16 + ln16 -> R = base/2 + i*8 + (ln16>>1),
  // S_phys = (4*(ln16&1)+quad) ^ (ln16>>1)   [i*8, wr*64, wc*32 == 0 mod 8].
  // Per-8-lane group S_phys covers all 8 values -> all 32 banks -> 0 conflicts.
  int Sp = (4 * (ln16 & 1) + quad) ^ (ln16 >> 1);
  const u16* aRd = As + (size_t)(wr * 64 + (ln16 >> 1)) * 64 + Sp * 8;
  const u16* bRd = Bs + (size_t)(wc * 32 + (ln16 >> 1)) * 64 + Sp * 8;

  for (int s = 0; s < nslot; ++s) {
    int cur = s & 3, tgt = (s + 3) & 3;
    const u16* aB = aRd + cur * SLOT;
    const u16* bB = bRd + cur * SLOT;
    short8 a[4], b[4];

    // ---- even phase: ms 0-3 ----
#pragma unroll
    for (int i = 0; i < 4; ++i) a[i] = *(const short8*)(aB + i * 512);
#pragma unroll
    for (int i = 0; i < 4; ++i) b[i] = *(const short8*)(bB + i * 512);
    if (s + 3 < nslot) STAGE_A(s + 3, tgt);
    __builtin_amdgcn_s_barrier();
    __builtin_amdgcn_s_setprio(1);
#pragma unroll
    for (int ms = 0; ms < 4; ++ms)
#pragma unroll
      for (int ns = 0; ns < 4; ++ns)
        acc[ms][ns] = __builtin_amdgcn_mfma_f32_16x16x32_bf16(a[ms], b[ns], acc[ms][ns], 0, 0, 0);
    __builtin_amdgcn_s_setprio(0);
    __builtin_amdgcn_s_barrier();

    // ---- odd phase: ms 4-7 (b[] held in registers) ----
#pragma unroll
    for (int i = 0; i < 4; ++i) a[i] = *(const short8*)(aB + (4 + i) * 512);
    if (s + 3 < nslot) {
      STAGE_B(s + 3, tgt);
      asm volatile("s_waitcnt vmcnt(8)" ::: "memory");   // retire slot s+1 only
    } else if (s + 2 < nslot) {
      asm volatile("s_waitcnt vmcnt(4)" ::: "memory");
    } else if (s + 1 < nslot) {
      asm volatile("s_waitcnt vmcnt(0)" ::: "memory");
    }
    __builtin_amdgcn_s_barrier();
    __builtin_amdgcn_s_setprio(1);
#pragma unroll
    for (int ms = 0; ms < 4; ++ms)
#pragma unroll
      for (int ns = 0; ns < 4; ++ns)
        acc[4 + ms][ns] = __builtin_amdgcn_mfma_f32_16x16x32_bf16(a[ms], b[ns], acc[4 + ms][ns], 0, 0, 0);
    __builtin_amdgcn_s_setprio(0);
    __builtin_amdgcn_s_barrier();
  }
#undef STAGE_A
#undef STAGE_B

#pragma unroll
  for (int ms = 0; ms < 8; ++ms)
#pragma unroll
    for (int ns = 0; ns < 4; ++ns) {
      int gcol = n0 + wc * 64 + ns * 16 + ln16;
      float bb = bias[gcol];
#pragma unroll
      for (int r = 0; r < 4; ++r) {
        int grow = m0 + wr * 128 + ms * 16 + quad * 4 + r;
        float v = acc[ms][ns][r] + bb;
        if (GELU) v = 0.5f * v * (1.f + erff(v * 0.70710678118654752f));
        C[(size_t)grow * N + gcol] = f2bf(v);
      }
    }
}

// ---------------------------------------------------------------------------
// Flash-style causal attention v3: QBLK=128, KVBLK=128, PAIRED q-tiles
// (harness-verified r15: total 384.7->365.1 us; attn dropped out of top-5).
// 8 waves x 16 q-rows per tile; grid (bh=32, p=8); ring-3 K/V LDS + counted
// vmcnt(4); fixed-max softmax; P in per-wave XOR-swizzled [16][128] LDS.
// LDS total = 128KB -> 1 block/CU, 8 waves.
// ---------------------------------------------------------------------------
__global__ __launch_bounds__(512) void attn_k(const u16* __restrict__ qkv,
                                              const u16* __restrict__ vT,
                                              u16* __restrict__ z) {
  __shared__ __align__(16) u16 Ks[3 * 8192];   // [ring][128 k-rows][64 d]  48KB
  __shared__ __align__(16) u16 Vs[3 * 8192];   // [ring][64 d-rows][128 k]  48KB
  __shared__ __align__(16) u16 Ps[8 * 2048];   // per-wave [16 q][128 k]    32KB
  int bh = blockIdx.x, p = blockIdx.y;
  int b = bh >> 4, h = bh & 15;
  int tA = p, tB = 15 - p;                     // tA <= 7 < 8 <= tB
  int t = threadIdx.x, w = t >> 6, lane = t & 63;
  int ln16 = lane & 15, quad = lane >> 4, e = ln16 & 7;

  // Q fragments for both tiles: rows tX*128 + w*16 + ln16, cols h*64 + kk*32 + quad*8
  short8 aq[2][2];
#pragma unroll
  for (int ti = 0; ti < 2; ++ti) {
    int tq = ti ? tB : tA;
    const u16* qrow = qkv + (size_t)(b * 2048 + tq * 128 + w * 16 + ln16) * 3072 + h * 64;
    aq[ti][0] = *(const short8*)(qrow + quad * 8);
    aq[ti][1] = *(const short8*)(qrow + 32 + quad * 8);
  }

  f32x4 zero4 = {0.f, 0.f, 0.f, 0.f};
  f32x4 o[2][4];
  float l_i[2][4];
#pragma unroll
  for (int ti = 0; ti < 2; ++ti)
#pragma unroll
    for (int n = 0; n < 4; ++n) { o[ti][n] = zero4; l_i[ti][n] = 0.f; }

  // --- staging geometry ---
  const u16* kB = qkv + (size_t)(b * 2048 + w * 16 + (lane >> 3)) * 3072
                + 1024 + h * 64 + (((lane & 7) ^ (lane >> 3))) * 8;
  const u16* vB0 = vT + ((size_t)(b * 16 + h) * 64 + w * 8 + (lane >> 4)) * 2048
                 + (((lane & 15) ^ (lane >> 4))) * 8;
  const u16* vB1 = vT + ((size_t)(b * 16 + h) * 64 + w * 8 + 4 + (lane >> 4)) * 2048
                 + (((lane & 15) ^ (4 + (lane >> 4)))) * 8;
  u16* kL = Ks + w * 16 * 64;    // + ring*8192
  u16* vL = Vs + w * 8 * 128;    // + ring*8192
  u16* psW = Ps + w * 2048;

#define STAGE(kt_, rg_) do {                                              \
    size_t kOff = (size_t)(kt_) * 128 * 3072;                             \
    u16* _kl = kL + (rg_) * 8192;                                         \
    load_lds16(kB + kOff, _kl);                                           \
    load_lds16(kB + kOff + (size_t)8 * 3072, _kl + 8 * 64);               \
    size_t vOff = (size_t)(kt_) * 128;                                    \
    u16* _vl = vL + (rg_) * 8192;                                         \
    load_lds16(vB0 + vOff, _vl);                                          \
    load_lds16(vB1 + vOff, _vl + 4 * 128);                                \
  } while (0)

  int nkt = tB + 1;
  STAGE(0, 0);

  for (int kt = 0; kt < nkt; ++kt) {
    int ring = kt % 3;
    if (kt + 1 < nkt) {
      STAGE(kt + 1, (kt + 1) % 3);
      asm volatile("s_waitcnt vmcnt(4)" ::: "memory");   // confirm tile kt
    } else {
      asm volatile("s_waitcnt vmcnt(0)" ::: "memory");
    }
    __builtin_amdgcn_s_barrier();

    const u16* ks = Ks + ring * 8192;
    const u16* vs = Vs + ring * 8192;
    int kg = kt * 128;

#pragma unroll
    for (int ti = 0; ti < 2; ++ti) {
      int tq = ti ? tB : tA;
      if (kt > tq) continue;            // only tile A can be out of range

      // --- QK^T: wave 16 q-rows x 128 k ---
      f32x4 s[8] = {zero4, zero4, zero4, zero4, zero4, zero4, zero4, zero4};
#pragma unroll
      for (int kk = 0; kk < 2; ++kk) {
        short8 a = aq[ti][kk];
        int slot = (kk * 4 + quad) ^ e;
#pragma unroll
        for (int n = 0; n < 8; ++n) {
          short8 kb = *(const short8*)&ks[(n * 16 + ln16) * 64 + slot * 8];
          s[n] = __builtin_amdgcn_mfma_f32_16x16x32_bf16(a, kb, s[n], 0, 0, 0);
        }
      }

      // --- softmax (fixed max), P -> swizzled per-wave LDS ---
      bool diag = (kt == tq);
      int qgb = tq * 128 + w * 16 + quad * 4;
#pragma unroll
      for (int r = 0; r < 4; ++r) {
        int q = quad * 4 + r, q7 = q & 7;
        int gq = qgb + r;
        float psum = 0.f;
#pragma unroll
        for (int n = 0; n < 8; ++n) {
          float pv = __expf(s[n][r] * 0.125f);
          if (diag && (kg + n * 16 + ln16 > gq)) pv = 0.f;
          psum += pv;
          psW[q * 128 + ((((n << 1) | (ln16 >> 3)) ^ q7) << 3) + e] = f2bf(pv);
        }
        l_i[ti][r] += psum;             // reduced over ln16 in epilogue
      }

      // --- PV: A = P[16q][128k], B = V[128k][64d] ---
#pragma unroll
      for (int kk = 0; kk < 4; ++kk) {
        int slot = (kk * 4 + quad) ^ e;
        short8 ap = *(const short8*)&psW[ln16 * 128 + slot * 8];
#pragma unroll
        for (int n = 0; n < 4; ++n) {
          short8 bv = *(const short8*)&vs[(n * 16 + ln16) * 128 + slot * 8];
          o[ti][n] = __builtin_amdgcn_mfma_f32_16x16x32_bf16(ap, bv, o[ti][n], 0, 0, 0);
        }
      }
    }
    // single barrier per iteration: ring-3 reuse distance guarantees >=1 full
    // barrier between last read of a slot and its restage.
  }
#undef STAGE

  // epilogue: reduce l over the 16 ln16 lanes (same q-row), normalize, store
#pragma unroll
  for (int ti = 0; ti < 2; ++ti) {
    int tq = ti ? tB : tA;
    float inv[4];
#pragma unroll
    for (int r = 0; r < 4; ++r) {
      float sum = l_i[ti][r];
#pragma unroll
      for (int off = 8; off; off >>= 1) sum += __shfl_xor(sum, off, 16);
      inv[r] = 1.f / sum;
    }
#pragma unroll
    for (int n = 0; n < 4; ++n)
#pragma unroll
      for (int r = 0; r < 4; ++r)
        z[(size_t)(b * 2048 + tq * 128 + w * 16 + quad * 4 + r) * 1024
          + h * 64 + n * 16 + ln16] = f2bf(o[ti][n][r] * inv[r]);
  }
}

// ---------------------------------------------------------------------------
extern "C" void kernel_launch(void* const* d_in, const int* in_sizes, int n_in,
                              void* d_out, int out_size, void* d_ws, size_t ws_size,
                              hipStream_t stream) {
  const float* resid_pre = (const float*)d_in[0];
  const float* ln1_w = (const float*)d_in[1];
  const float* ln1_b = (const float*)d_in[2];
  const float* W_Q  = (const float*)d_in[3];
  const float* b_Q  = (const float*)d_in[4];
  const float* W_K  = (const float*)d_in[5];
  const float* b_K  = (const float*)d_in[6];
  const float* W_V  = (const float*)d_in[7];
  const float* b_V  = (const float*)d_in[8];
  const float* W_O  = (const float*)d_in[9];
  const float* b_O  = (const float*)d_in[10];
  const float* ln2_w = (const float*)d_in[11];
  const float* ln2_b = (const float*)d_in[12];
  const float* W_in  = (const float*)d_in[13];
  const float* b_in  = (const float*)d_in[14];
  const float* W_out = (const float*)d_in[15];
  const float* b_out = (const float*)d_in[16];
  float* out = (float*)d_out;

  char* w = (char*)d_ws;
  u16* WqkvT = (u16*)w;  w += (size_t)3072 * 1024 * 2;
  u16* WoT   = (u16*)w;  w += (size_t)1024 * 1024 * 2;
  u16* WinT  = (u16*)w;  w += (size_t)4096 * 1024 * 2;
  u16* WoutT = (u16*)w;  w += (size_t)1024 * 4096 * 2;
  float* qkvBias = (float*)w; w += 3072 * 4;
  u16* xln   = (u16*)w;  w += (size_t)4096 * 1024 * 2;   // reused as y after LN2
  float* resid_mid = (float*)w; w += (size_t)4096 * 1024 * 4;
  u16* qkvBuf = (u16*)w; w += (size_t)4096 * 3072 * 2;
  u16* zBuf  = (u16*)w;  w += (size_t)4096 * 1024 * 2;
  u16* vTBuf = (u16*)w;  w += (size_t)32 * 64 * 2048 * 2;
  u16* hBuf  = qkvBuf;   // 32 MB: reuses qkvBuf+zBuf region (dead by then)

  dim3 tb(32, 8);
  // Weight transposes (fp32 -> bf16) into BT[N][K] layouts
  transpose_k<<<dim3(2, 32, 16), tb, 0, stream>>>(W_Q, WqkvT,                1024, 64, 65536, 65536);
  transpose_k<<<dim3(2, 32, 16), tb, 0, stream>>>(W_K, WqkvT + 1024 * 1024,  1024, 64, 65536, 65536);
  transpose_k<<<dim3(2, 32, 16), tb, 0, stream>>>(W_V, WqkvT + 2048 * 1024,  1024, 64, 65536, 65536);
  transpose_k<<<dim3(32, 32, 1), tb, 0, stream>>>(W_O,  WoT,   1024, 1024, 0, 0);
  transpose_k<<<dim3(128, 32, 1), tb, 0, stream>>>(W_in, WinT,  1024, 4096, 0, 0);
  transpose_k<<<dim3(32, 128, 1), tb, 0, stream>>>(W_out, WoutT, 4096, 1024, 0, 0);
  build_qkv_bias<<<12, 256, 0, stream>>>(b_Q, b_K, b_V, qkvBias);

  // LN1: fp32 resid_pre -> bf16 xln
  ln_k<<<4096, 256, 0, stream>>>(resid_pre, ln1_w, ln1_b, xln);
  // QKV projection (fused): [4096,1024] x [1024,3072] -> bf16 (256^2 pipelined)
  gemm256_k<false><<<dim3(12, 16), 512, 0, stream>>>(
      xln, WqkvT, qkvBias, qkvBuf, 4096, 3072, 1024);
  // V transpose for attention B-fragments
  transpose_v_k<<<dim3(2, 64, 32), tb, 0, stream>>>(qkvBuf, vTBuf);
  // Causal attention v3: QBLK=128/KVBLK=128, paired, ring-3, XCD-grouped grid
  attn_k<<<dim3(32, 8, 1), 512, 0, stream>>>(qkvBuf, vTBuf, zBuf);
  // Output projection + resid_pre -> resid_mid (fp32); 128x64 tiles, 512 blocks
  gemm_k<64, true, false, true><<<dim3(16, 32), 256, 0, stream>>>(
      zBuf, WoT, b_O, resid_pre, resid_mid, 4096, 1024, 1024);
  // LN2: fp32 resid_mid -> bf16 y (xln reused)
  ln_k<<<4096, 256, 0, stream>>>(resid_mid, ln2_w, ln2_b, xln);
  // MLP up + exact GELU -> bf16 h (256^2 pipelined)
  gemm256_k<true><<<dim3(16, 16), 512, 0, stream>>>(
      xln, WinT, b_in, hBuf, 4096, 4096, 1024);
  // MLP down + resid_mid -> output (fp32); 128x64 tiles, 512 blocks
  gemm_k<64, true, false, true><<<dim3(16, 32), 256, 0, stream>>>(
      hBuf, WoutT, b_out, resid_mid, out, 4096, 1024, 4096);
}

// Round 18
// 364.963 us; speedup vs baseline: 1.0966x; 1.0966x over previous
//
#include <hip/hip_runtime.h>
#include <cstddef>

typedef unsigned short u16;
using short8 = __attribute__((ext_vector_type(8))) short;
using f32x4  = __attribute__((ext_vector_type(4))) float;

__device__ __forceinline__ float bf2f(u16 u) {
  union { unsigned int i; float f; } v; v.i = ((unsigned int)u) << 16; return v.f;
}
__device__ __forceinline__ u16 f2bf(float f) {
  __bf16 h = (__bf16)f;
  return __builtin_bit_cast(unsigned short, h);
}

// async global(16B/lane) -> LDS. lds dest must be wave-uniform base; HW adds lane*16.
__device__ __forceinline__ void load_lds16(const u16* g, u16* l) {
  __builtin_amdgcn_global_load_lds((const __attribute__((address_space(1))) void*)g,
                                   (__attribute__((address_space(3))) void*)l, 16, 0, 0);
}

// ---------------------------------------------------------------------------
// Batched 2D transpose + fp32->bf16: in fp32 [R][C] -> out bf16 [C][R].
// Grid: (C/32, R/32, nBatch), block (32,8). R,C multiples of 32.
// ---------------------------------------------------------------------------
__global__ __launch_bounds__(256) void transpose_k(const float* __restrict__ in,
                                                   u16* __restrict__ out,
                                                   int R, int C,
                                                   long inB, long outB) {
  __shared__ float tile[32][33];
  long zb = blockIdx.z;
  in  += zb * inB;
  out += zb * outB;
  int c0 = blockIdx.x * 32, r0 = blockIdx.y * 32;
  int tx = threadIdx.x, ty = threadIdx.y;
#pragma unroll
  for (int i = 0; i < 32; i += 8)
    tile[ty + i][tx] = in[(long)(r0 + ty + i) * C + c0 + tx];
  __syncthreads();
#pragma unroll
  for (int i = 0; i < 32; i += 8)
    out[(long)(c0 + ty + i) * R + r0 + tx] = f2bf(tile[tx][ty + i]);
}

// ---------------------------------------------------------------------------
// V transpose: qkv [b*2048][3072] (V at col 2048+h*64+e) -> vT[(b*16+h)*64+e][2048]
// Grid (2, 64, 32), block (32,8).
// ---------------------------------------------------------------------------
__global__ __launch_bounds__(256) void transpose_v_k(const u16* __restrict__ qkv,
                                                     u16* __restrict__ vT) {
  __shared__ u16 tile[32][33];
  int bh = blockIdx.z;
  int b = bh >> 4, h = bh & 15;
  const u16* in = qkv + (size_t)b * 2048 * 3072 + 2048 + h * 64;
  u16* out = vT + (size_t)bh * 64 * 2048;
  int e0 = blockIdx.x * 32, s0 = blockIdx.y * 32;
  int tx = threadIdx.x, ty = threadIdx.y;
#pragma unroll
  for (int i = 0; i < 32; i += 8)
    tile[ty + i][tx] = in[(size_t)(s0 + ty + i) * 3072 + e0 + tx];
  __syncthreads();
#pragma unroll
  for (int i = 0; i < 32; i += 8)
    out[(size_t)(e0 + ty + i) * 2048 + s0 + tx] = tile[tx][ty + i];
}

// ---------------------------------------------------------------------------
// Combined QKV bias (fp32): [0..1023]=b_Q, [1024..2047]=b_K, [2048..3071]=b_V
// ---------------------------------------------------------------------------
__global__ void build_qkv_bias(const float* __restrict__ bQ, const float* __restrict__ bK,
                               const float* __restrict__ bV, float* __restrict__ out) {
  int i = blockIdx.x * 256 + threadIdx.x;
  float v;
  if (i < 1024) v = bQ[i];
  else if (i < 2048) v = bK[i - 1024];
  else v = bV[i - 2048];
  out[i] = v;
}

// ---------------------------------------------------------------------------
// LayerNorm over D=1024, fp32 in -> bf16 out. One block (256 thr) per row.
// ---------------------------------------------------------------------------
__global__ __launch_bounds__(256) void ln_k(const float* __restrict__ inp,
                                            const float* __restrict__ w,
                                            const float* __restrict__ bias,
                                            u16* __restrict__ out) {
  __shared__ float red[2][4];
  int row = blockIdx.x, t = threadIdx.x;
  int wave = t >> 6, lane = t & 63;
  size_t base = (size_t)row * 1024 + t * 4;
  float4 f = *(const float4*)(inp + base);
  float v[4] = {f.x, f.y, f.z, f.w};
  float s = v[0] + v[1] + v[2] + v[3];
#pragma unroll
  for (int off = 32; off; off >>= 1) s += __shfl_xor(s, off, 64);
  if (lane == 0) red[0][wave] = s;
  __syncthreads();
  float mean = (red[0][0] + red[0][1] + red[0][2] + red[0][3]) * (1.f / 1024.f);
  float c[4]; float sq = 0.f;
#pragma unroll
  for (int j = 0; j < 4; ++j) { c[j] = v[j] - mean; sq += c[j] * c[j]; }
#pragma unroll
  for (int off = 32; off; off >>= 1) sq += __shfl_xor(sq, off, 64);
  if (lane == 0) red[1][wave] = sq;
  __syncthreads();
  float var = (red[1][0] + red[1][1] + red[1][2] + red[1][3]) * (1.f / 1024.f);
  float inv = 1.f / sqrtf(var + 1e-5f);
  float4 wv = *(const float4*)(w + t * 4);
  float4 bv = *(const float4*)(bias + t * 4);
  out[base + 0] = f2bf(c[0] * inv * wv.x + bv.x);
  out[base + 1] = f2bf(c[1] * inv * wv.y + bv.y);
  out[base + 2] = f2bf(c[2] * inv * wv.z + bv.z);
  out[base + 3] = f2bf(c[3] * inv * wv.w + bv.w);
}

// ---------------------------------------------------------------------------
// m97-class MFMA GEMM: C[M][N] = A[M][K](bf16) * BT[N][K](bf16)^T + bias(f32)
// 128xTN tile (TN=128 or 64), BK=64, global_load_lds 16B staging, XOR-swizzled
// LDS (16B slot = seg ^ (row&7)). 4 waves in 2x2; wave tile 64 x TN/2.
// Grid (N/TN, M/128), block 256.  (harness-verified: 0 bank conflicts)
// ---------------------------------------------------------------------------
template<int TN, bool RESIDF, bool GELU, bool OUTF32>
__global__ __launch_bounds__(256, 2) void gemm_k(const u16* __restrict__ A,
                                                 const u16* __restrict__ BT,
                                                 const float* __restrict__ bias,
                                                 const float* __restrict__ resid,
                                                 void* __restrict__ Cout,
                                                 int M, int N, int K) {
  constexpr int NS = TN / 32;   // 16-col n-subtiles per wave
  __shared__ u16 As[128 * 64];
  __shared__ u16 Bs[TN * 64];
  int n0 = blockIdx.x * TN, m0 = blockIdx.y * 128;
  int t = threadIdx.x;
  int wave = t >> 6, lane = t & 63;
  int wr = wave >> 1, wc = wave & 1;
  int ln16 = lane & 15, quad = lane >> 4;

  f32x4 acc[4][NS];
#pragma unroll
  for (int i = 0; i < 4; ++i)
#pragma unroll
    for (int j = 0; j < NS; ++j) acc[i][j] = (f32x4){0.f, 0.f, 0.f, 0.f};

  int lrow8 = lane >> 3;
  int gseg  = (lane & 7) ^ lrow8;
  const u16* aG = A  + (size_t)(m0 + wave * 8 + lrow8) * K + gseg * 8;
  const u16* bG = BT + (size_t)(n0 + wave * 8 + lrow8) * K + gseg * 8;
  u16* aL = As + wave * 8 * 64;
  u16* bL = Bs + wave * 8 * 64;

  int e = ln16 & 7;
  int arow = wr * 64 + ln16;
  int brow = wc * (TN / 2) + ln16;

  for (int k0 = 0; k0 < K; k0 += 64) {
    __syncthreads();
#pragma unroll
    for (int i = 0; i < 4; ++i)
      load_lds16(aG + (size_t)i * 32 * K + k0, aL + i * 32 * 64);
#pragma unroll
    for (int i = 0; i < TN / 32; ++i)
      load_lds16(bG + (size_t)i * 32 * K + k0, bL + i * 32 * 64);
    __syncthreads();
#pragma unroll
    for (int kk = 0; kk < 2; ++kk) {
      int slot = (kk * 4 + quad) ^ e;
      short8 af[4], bf[NS];
#pragma unroll
      for (int ms = 0; ms < 4; ++ms)
        af[ms] = *(const short8*)&As[(arow + ms * 16) * 64 + slot * 8];
#pragma unroll
      for (int ns = 0; ns < NS; ++ns)
        bf[ns] = *(const short8*)&Bs[(brow + ns * 16) * 64 + slot * 8];
#pragma unroll
      for (int ms = 0; ms < 4; ++ms)
#pragma unroll
        for (int ns = 0; ns < NS; ++ns)
          acc[ms][ns] = __builtin_amdgcn_mfma_f32_16x16x32_bf16(af[ms], bf[ns], acc[ms][ns], 0, 0, 0);
    }
  }

#pragma unroll
  for (int ms = 0; ms < 4; ++ms)
#pragma unroll
    for (int ns = 0; ns < NS; ++ns)
#pragma unroll
      for (int r = 0; r < 4; ++r) {
        int grow = m0 + wr * 64 + ms * 16 + quad * 4 + r;
        int gcol = n0 + wc * (TN / 2) + ns * 16 + ln16;
        size_t idx = (size_t)grow * N + gcol;
        float v = acc[ms][ns][r] + bias[gcol];
        if (GELU) v = 0.5f * v * (1.f + erff(v * 0.70710678118654752f));
        if (RESIDF) v += resid[idx];
        if (OUTF32) ((float*)Cout)[idx] = v;
        else        ((u16*)Cout)[idx] = f2bf(v);
      }
}

// ---------------------------------------------------------------------------
// 256x256 MFMA GEMM v2 (r16): gemm_k geometry scaled up + ring-2 counted-vmcnt.
// C[M][N](bf16) = A[M][K](bf16) * BT[N][K]^T + bias, optional exact GELU.
// 512 threads = 8 waves in 2(M) x 4(N); per-wave output 128x64.
// LDS: ring of 2 full BK=64 slots; slot = {A[256][64], B[256][64]} bf16
// (128B rows) = 64KB; ring-2 = 128KB -> 1 block/CU.
//   - Staging: EXACTLY gemm_k's measured-good pattern: 8-lane group covers one
//     CONTIGUOUS 128B row with intra-row slot perm seg=(lane&7)^(row&7).
//     (r15 lesson: permutation must stay inside a contiguous block; the 64B
//     two-row scramble halved HBM BW.)
//   - Read: gemm_k's measured-0-conflict pattern: slot=(kk*4+quad)^(ln16&7).
//   - Pipeline: STAGE(s+1) issued BEFORE compute(s); vmcnt(8) retires exactly
//     STAGE(s) (8 loads/STAGE, 16 outstanding); end-of-iter barrier separates
//     compute(s) reads of slot s&1 from iter s+1's restage of that slot.
// Requires K%64==0, K>=128, M%256==0, N%256==0.
// ---------------------------------------------------------------------------
template<bool GELU>
__global__ __launch_bounds__(512, 2) void gemm256_k(const u16* __restrict__ A,
                                                    const u16* __restrict__ BT,
                                                    const float* __restrict__ bias,
                                                    u16* __restrict__ C,
                                                    int M, int N, int K) {
  constexpr int SLOT = 256 * 64;              // u16 per ring slot = 32 KB
  __shared__ __align__(16) u16 As[2 * SLOT];  // 64 KB
  __shared__ __align__(16) u16 Bs[2 * SLOT];  // 64 KB
  int n0 = blockIdx.x * 256, m0 = blockIdx.y * 256;
  int t = threadIdx.x;
  int w = t >> 6, lane = t & 63;
  int wr = w >> 2, wc = w & 3;
  int ln16 = lane & 15, quad = lane >> 4;

  f32x4 acc[8][4];
#pragma unroll
  for (int i = 0; i < 8; ++i)
#pragma unroll
    for (int j = 0; j < 4; ++j) acc[i][j] = (f32x4){0.f, 0.f, 0.f, 0.f};

  // Staging: instr i covers LDS rows i*64 + (t>>3); thread t writes 16B at
  // linear t*16B (+ i*4096 u16). Global: row m0 + i*64 + (t>>3), 16B seg
  // (t&7)^((t>>3)&7) -> per 8-lane group a contiguous 128B row, permuted.
  int r8 = t >> 3;                      // 0..63
  int seg = (t & 7) ^ (r8 & 7);
  const u16* aG0 = A  + (size_t)(m0 + r8) * K + seg * 8;
  const u16* bG0 = BT + (size_t)(n0 + r8) * K + seg * 8;
  u16* aLw = As + w * 512;              // wave-uniform; +tg*SLOT, +i*4096
  u16* bLw = Bs + w * 512;

#define STAGE(s_, tg_) do {                                              \
    const u16* _ga = aG0 + (size_t)(s_) * 64;                            \
    const u16* _gb = bG0 + (size_t)(s_) * 64;                            \
    u16* _la = aLw + (tg_) * SLOT;                                       \
    u16* _lb = bLw + (tg_) * SLOT;                                       \
    load_lds16(_ga,                       _la);                          \
    load_lds16(_ga + (size_t)64 * K,      _la + 4096);                   \
    load_lds16(_ga + (size_t)128 * K,     _la + 8192);                   \
    load_lds16(_ga + (size_t)192 * K,     _la + 12288);                  \
    load_lds16(_gb,                       _lb);                          \
    load_lds16(_gb + (size_t)64 * K,      _lb + 4096);                   \
    load_lds16(_gb + (size_t)128 * K,     _lb + 8192);                   \
    load_lds16(_gb + (size_t)192 * K,     _lb + 12288);                  \
  } while (0)

  STAGE(0, 0);

  int e = ln16 & 7;
  int nslot = K >> 6;
  const u16* aRd = As + (size_t)(wr * 128 + ln16) * 64;   // + ms*16*64 + slot*8
  const u16* bRd = Bs + (size_t)(wc * 64 + ln16) * 64;    // + ns*16*64 + slot*8

  for (int s = 0; s < nslot; ++s) {
    int cur = s & 1;
    if (s + 1 < nslot) {
      STAGE(s + 1, cur ^ 1);
      asm volatile("s_waitcnt vmcnt(8)" ::: "memory");   // retire STAGE(s)
    } else {
      asm volatile("s_waitcnt vmcnt(0)" ::: "memory");
    }
    __builtin_amdgcn_s_barrier();      // slot cur staged by all waves

    const u16* aB = aRd + cur * SLOT;
    const u16* bB = bRd + cur * SLOT;
    __builtin_amdgcn_s_setprio(1);
#pragma unroll
    for (int kk = 0; kk < 2; ++kk) {
      int slot = (kk * 4 + quad) ^ e;
      short8 bf[4];
#pragma unroll
      for (int ns = 0; ns < 4; ++ns)
        bf[ns] = *(const short8*)(bB + ns * 1024 + slot * 8);
#pragma unroll
      for (int ms = 0; ms < 8; ++ms) {
        short8 af = *(const short8*)(aB + ms * 1024 + slot * 8);
#pragma unroll
        for (int ns = 0; ns < 4; ++ns)
          acc[ms][ns] = __builtin_amdgcn_mfma_f32_16x16x32_bf16(af, bf[ns], acc[ms][ns], 0, 0, 0);
      }
    }
    __builtin_amdgcn_s_setprio(0);
    __builtin_amdgcn_s_barrier();      // reads of slot cur done before restage
  }
#undef STAGE

#pragma unroll
  for (int ms = 0; ms < 8; ++ms)
#pragma unroll
    for (int ns = 0; ns < 4; ++ns) {
      int gcol = n0 + wc * 64 + ns * 16 + ln16;
      float bb = bias[gcol];
#pragma unroll
      for (int r = 0; r < 4; ++r) {
        int grow = m0 + wr * 128 + ms * 16 + quad * 4 + r;
        float v = acc[ms][ns][r] + bb;
        if (GELU) v = 0.5f * v * (1.f + erff(v * 0.70710678118654752f));
        C[(size_t)grow * N + gcol] = f2bf(v);
      }
    }
}

// ---------------------------------------------------------------------------
// Flash-style causal attention v3: QBLK=128, KVBLK=128, PAIRED q-tiles
// (harness-verified r15: total 384.7->365.1 us; attn dropped out of top-5).
// 8 waves x 16 q-rows per tile; grid (bh=32, p=8); ring-3 K/V LDS + counted
// vmcnt(4); fixed-max softmax; P in per-wave XOR-swizzled [16][128] LDS.
// LDS total = 128KB -> 1 block/CU, 8 waves.
// ---------------------------------------------------------------------------
__global__ __launch_bounds__(512) void attn_k(const u16* __restrict__ qkv,
                                              const u16* __restrict__ vT,
                                              u16* __restrict__ z) {
  __shared__ __align__(16) u16 Ks[3 * 8192];   // [ring][128 k-rows][64 d]  48KB
  __shared__ __align__(16) u16 Vs[3 * 8192];   // [ring][64 d-rows][128 k]  48KB
  __shared__ __align__(16) u16 Ps[8 * 2048];   // per-wave [16 q][128 k]    32KB
  int bh = blockIdx.x, p = blockIdx.y;
  int b = bh >> 4, h = bh & 15;
  int tA = p, tB = 15 - p;                     // tA <= 7 < 8 <= tB
  int t = threadIdx.x, w = t >> 6, lane = t & 63;
  int ln16 = lane & 15, quad = lane >> 4, e = ln16 & 7;

  // Q fragments for both tiles: rows tX*128 + w*16 + ln16, cols h*64 + kk*32 + quad*8
  short8 aq[2][2];
#pragma unroll
  for (int ti = 0; ti < 2; ++ti) {
    int tq = ti ? tB : tA;
    const u16* qrow = qkv + (size_t)(b * 2048 + tq * 128 + w * 16 + ln16) * 3072 + h * 64;
    aq[ti][0] = *(const short8*)(qrow + quad * 8);
    aq[ti][1] = *(const short8*)(qrow + 32 + quad * 8);
  }

  f32x4 zero4 = {0.f, 0.f, 0.f, 0.f};
  f32x4 o[2][4];
  float l_i[2][4];
#pragma unroll
  for (int ti = 0; ti < 2; ++ti)
#pragma unroll
    for (int n = 0; n < 4; ++n) { o[ti][n] = zero4; l_i[ti][n] = 0.f; }

  // --- staging geometry ---
  const u16* kB = qkv + (size_t)(b * 2048 + w * 16 + (lane >> 3)) * 3072
                + 1024 + h * 64 + (((lane & 7) ^ (lane >> 3))) * 8;
  const u16* vB0 = vT + ((size_t)(b * 16 + h) * 64 + w * 8 + (lane >> 4)) * 2048
                 + (((lane & 15) ^ (lane >> 4))) * 8;
  const u16* vB1 = vT + ((size_t)(b * 16 + h) * 64 + w * 8 + 4 + (lane >> 4)) * 2048
                 + (((lane & 15) ^ (4 + (lane >> 4)))) * 8;
  u16* kL = Ks + w * 16 * 64;    // + ring*8192
  u16* vL = Vs + w * 8 * 128;    // + ring*8192
  u16* psW = Ps + w * 2048;

#define STAGE(kt_, rg_) do {                                              \
    size_t kOff = (size_t)(kt_) * 128 * 3072;                             \
    u16* _kl = kL + (rg_) * 8192;                                         \
    load_lds16(kB + kOff, _kl);                                           \
    load_lds16(kB + kOff + (size_t)8 * 3072, _kl + 8 * 64);               \
    size_t vOff = (size_t)(kt_) * 128;                                    \
    u16* _vl = vL + (rg_) * 8192;                                         \
    load_lds16(vB0 + vOff, _vl);                                          \
    load_lds16(vB1 + vOff, _vl + 4 * 128);                                \
  } while (0)

  int nkt = tB + 1;
  STAGE(0, 0);

  for (int kt = 0; kt < nkt; ++kt) {
    int ring = kt % 3;
    if (kt + 1 < nkt) {
      STAGE(kt + 1, (kt + 1) % 3);
      asm volatile("s_waitcnt vmcnt(4)" ::: "memory");   // confirm tile kt
    } else {
      asm volatile("s_waitcnt vmcnt(0)" ::: "memory");
    }
    __builtin_amdgcn_s_barrier();

    const u16* ks = Ks + ring * 8192;
    const u16* vs = Vs + ring * 8192;
    int kg = kt * 128;

#pragma unroll
    for (int ti = 0; ti < 2; ++ti) {
      int tq = ti ? tB : tA;
      if (kt > tq) continue;            // only tile A can be out of range

      // --- QK^T: wave 16 q-rows x 128 k ---
      f32x4 s[8] = {zero4, zero4, zero4, zero4, zero4, zero4, zero4, zero4};
#pragma unroll
      for (int kk = 0; kk < 2; ++kk) {
        short8 a = aq[ti][kk];
        int slot = (kk * 4 + quad) ^ e;
#pragma unroll
        for (int n = 0; n < 8; ++n) {
          short8 kb = *(const short8*)&ks[(n * 16 + ln16) * 64 + slot * 8];
          s[n] = __builtin_amdgcn_mfma_f32_16x16x32_bf16(a, kb, s[n], 0, 0, 0);
        }
      }

      // --- softmax (fixed max), P -> swizzled per-wave LDS ---
      bool diag = (kt == tq);
      int qgb = tq * 128 + w * 16 + quad * 4;
#pragma unroll
      for (int r = 0; r < 4; ++r) {
        int q = quad * 4 + r, q7 = q & 7;
        int gq = qgb + r;
        float psum = 0.f;
#pragma unroll
        for (int n = 0; n < 8; ++n) {
          float pv = __expf(s[n][r] * 0.125f);
          if (diag && (kg + n * 16 + ln16 > gq)) pv = 0.f;
          psum += pv;
          psW[q * 128 + ((((n << 1) | (ln16 >> 3)) ^ q7) << 3) + e] = f2bf(pv);
        }
        l_i[ti][r] += psum;             // reduced over ln16 in epilogue
      }

      // --- PV: A = P[16q][128k], B = V[128k][64d] ---
#pragma unroll
      for (int kk = 0; kk < 4; ++kk) {
        int slot = (kk * 4 + quad) ^ e;
        short8 ap = *(const short8*)&psW[ln16 * 128 + slot * 8];
#pragma unroll
        for (int n = 0; n < 4; ++n) {
          short8 bv = *(const short8*)&vs[(n * 16 + ln16) * 128 + slot * 8];
          o[ti][n] = __builtin_amdgcn_mfma_f32_16x16x32_bf16(ap, bv, o[ti][n], 0, 0, 0);
        }
      }
    }
    // single barrier per iteration: ring-3 reuse distance guarantees >=1 full
    // barrier between last read of a slot and its restage.
  }
#undef STAGE

  // epilogue: reduce l over the 16 ln16 lanes (same q-row), normalize, store
#pragma unroll
  for (int ti = 0; ti < 2; ++ti) {
    int tq = ti ? tB : tA;
    float inv[4];
#pragma unroll
    for (int r = 0; r < 4; ++r) {
      float sum = l_i[ti][r];
#pragma unroll
      for (int off = 8; off; off >>= 1) sum += __shfl_xor(sum, off, 16);
      inv[r] = 1.f / sum;
    }
#pragma unroll
    for (int n = 0; n < 4; ++n)
#pragma unroll
      for (int r = 0; r < 4; ++r)
        z[(size_t)(b * 2048 + tq * 128 + w * 16 + quad * 4 + r) * 1024
          + h * 64 + n * 16 + ln16] = f2bf(o[ti][n][r] * inv[r]);
  }
}

// ---------------------------------------------------------------------------
extern "C" void kernel_launch(void* const* d_in, const int* in_sizes, int n_in,
                              void* d_out, int out_size, void* d_ws, size_t ws_size,
                              hipStream_t stream) {
  const float* resid_pre = (const float*)d_in[0];
  const float* ln1_w = (const float*)d_in[1];
  const float* ln1_b = (const float*)d_in[2];
  const float* W_Q  = (const float*)d_in[3];
  const float* b_Q  = (const float*)d_in[4];
  const float* W_K  = (const float*)d_in[5];
  const float* b_K  = (const float*)d_in[6];
  const float* W_V  = (const float*)d_in[7];
  const float* b_V  = (const float*)d_in[8];
  const float* W_O  = (const float*)d_in[9];
  const float* b_O  = (const float*)d_in[10];
  const float* ln2_w = (const float*)d_in[11];
  const float* ln2_b = (const float*)d_in[12];
  const float* W_in  = (const float*)d_in[13];
  const float* b_in  = (const float*)d_in[14];
  const float* W_out = (const float*)d_in[15];
  const float* b_out = (const float*)d_in[16];
  float* out = (float*)d_out;

  char* w = (char*)d_ws;
  u16* WqkvT = (u16*)w;  w += (size_t)3072 * 1024 * 2;
  u16* WoT   = (u16*)w;  w += (size_t)1024 * 1024 * 2;
  u16* WinT  = (u16*)w;  w += (size_t)4096 * 1024 * 2;
  u16* WoutT = (u16*)w;  w += (size_t)1024 * 4096 * 2;
  float* qkvBias = (float*)w; w += 3072 * 4;
  u16* xln   = (u16*)w;  w += (size_t)4096 * 1024 * 2;   // reused as y after LN2
  float* resid_mid = (float*)w; w += (size_t)4096 * 1024 * 4;
  u16* qkvBuf = (u16*)w; w += (size_t)4096 * 3072 * 2;
  u16* zBuf  = (u16*)w;  w += (size_t)4096 * 1024 * 2;
  u16* vTBuf = (u16*)w;  w += (size_t)32 * 64 * 2048 * 2;
  u16* hBuf  = qkvBuf;   // 32 MB: reuses qkvBuf+zBuf region (dead by then)

  dim3 tb(32, 8);
  // Weight transposes (fp32 -> bf16) into BT[N][K] layouts
  transpose_k<<<dim3(2, 32, 16), tb, 0, stream>>>(W_Q, WqkvT,                1024, 64, 65536, 65536);
  transpose_k<<<dim3(2, 32, 16), tb, 0, stream>>>(W_K, WqkvT + 1024 * 1024,  1024, 64, 65536, 65536);
  transpose_k<<<dim3(2, 32, 16), tb, 0, stream>>>(W_V, WqkvT + 2048 * 1024,  1024, 64, 65536, 65536);
  transpose_k<<<dim3(32, 32, 1), tb, 0, stream>>>(W_O,  WoT,   1024, 1024, 0, 0);
  transpose_k<<<dim3(128, 32, 1), tb, 0, stream>>>(W_in, WinT,  1024, 4096, 0, 0);
  transpose_k<<<dim3(32, 128, 1), tb, 0, stream>>>(W_out, WoutT, 4096, 1024, 0, 0);
  build_qkv_bias<<<12, 256, 0, stream>>>(b_Q, b_K, b_V, qkvBias);

  // LN1: fp32 resid_pre -> bf16 xln
  ln_k<<<4096, 256, 0, stream>>>(resid_pre, ln1_w, ln1_b, xln);
  // QKV projection (fused): [4096,1024] x [1024,3072] -> bf16 (256^2 ring-2)
  gemm256_k<false><<<dim3(12, 16), 512, 0, stream>>>(
      xln, WqkvT, qkvBias, qkvBuf, 4096, 3072, 1024);
  // V transpose for attention B-fragments
  transpose_v_k<<<dim3(2, 64, 32), tb, 0, stream>>>(qkvBuf, vTBuf);
  // Causal attention v3: QBLK=128/KVBLK=128, paired, ring-3, XCD-grouped grid
  attn_k<<<dim3(32, 8, 1), 512, 0, stream>>>(qkvBuf, vTBuf, zBuf);
  // Output projection + resid_pre -> resid_mid (fp32); 128x64 tiles, 512 blocks
  gemm_k<64, true, false, true><<<dim3(16, 32), 256, 0, stream>>>(
      zBuf, WoT, b_O, resid_pre, resid_mid, 4096, 1024, 1024);
  // LN2: fp32 resid_mid -> bf16 y (xln reused)
  ln_k<<<4096, 256, 0, stream>>>(resid_mid, ln2_w, ln2_b, xln);
  // MLP up + exact GELU -> bf16 h (256^2 ring-2)
  gemm256_k<true><<<dim3(16, 16), 512, 0, stream>>>(
      xln, WinT, b_in, hBuf, 4096, 4096, 1024);
  // MLP down + resid_mid -> output (fp32); 128x64 tiles, 512 blocks
  gemm_k<64, true, false, true><<<dim3(16, 32), 256, 0, stream>>>(
      hBuf, WoutT, b_out, resid_mid, out, 4096, 1024, 4096);
}